// Round 5
// baseline (232.348 us; speedup 1.0000x reference)
//
#include <hip/hip_runtime.h>

#define B_  8
#define QL_ 128
#define ML_ 1024
#define KS_ 512
#define H_  256

// ws layout (floats):
//   Eq = exp2(2log2e*qproj): [B][QL][H]   @ 0        (262144 floats)
//   Ek = exp2(2log2e*kproj): [B][ML][H]   @ 262144   (2097152 floats)
//   mask canonical uint8 [B*ML]           @ 2359296  (8192 B = 2048 floats)
//   Whi bf16 [512][512]                   @ 2361344  (131072 floats)
//   Wlo bf16 [512][512]                   @ 2492416  (131072 floats)
//   Xhi bf16 [9216][512]                  @ 2623488  (2359296 floats)
//   Xlo bf16 [9216][512]                  @ 4982784  (2359296 floats)
#define QP_OFF 0
#define KP_OFF 262144
#define MASK_OFF 2359296
#define WH_OFF 2361344
#define WL_OFF 2492416
#define XH_OFF 2623488
#define XL_OFF 4982784

typedef __attribute__((ext_vector_type(8))) short bfrag;   // 8 bf16 (4 VGPR)
typedef __attribute__((ext_vector_type(4))) float f4acc;   // MFMA acc

// fp32 -> (hi,lo) bf16 split. hi = truncation (residual <= 2^-8|x|, captured
// exactly by fp32 subtract); lo = RNE of residual (final err <= 2^-17|x|).
// Dropped lo*lo cross term <= 2^-16 rel. Same math as R2..R4 (bit-identical).
__device__ __forceinline__ void split1(float v, unsigned& h, unsigned& lo) {
    unsigned u  = __float_as_uint(v);
    unsigned hb = u & 0xFFFF0000u;
    float    lf = v - __uint_as_float(hb);           // exact
    unsigned ul = __float_as_uint(lf);
    unsigned lr = ul + 0x7FFFu + ((ul >> 16) & 1u);  // RNE
    h  = u >> 16;
    lo = lr >> 16;
}

__device__ __forceinline__ void split4(const float4& a, unsigned& h01, unsigned& h23,
                                       unsigned& l01, unsigned& l23) {
    unsigned h[4], l[4];
    split1(a.x, h[0], l[0]); split1(a.y, h[1], l[1]);
    split1(a.z, h[2], l[2]); split1(a.w, h[3], l[3]);
    h01 = h[0] | (h[1] << 16); h23 = h[2] | (h[3] << 16);
    l01 = l[0] | (l[1] << 16); l23 = l[2] | (l[3] << 16);
}

// ---------------------------------------------------------------------------
// Prep kernel: one-time bf16 hi/lo split of W (1 MB) AND X=query|memory
// (18.9 MB) + mask canonicalizer. Memory-bound. (unchanged from R4)
// ---------------------------------------------------------------------------
__global__ __launch_bounds__(256) void prep_kernel(
    const float* __restrict__ query, const float* __restrict__ memory,
    const float* __restrict__ Wq, const float* __restrict__ Wk,
    unsigned short* __restrict__ Whi, unsigned short* __restrict__ Wlo,
    unsigned short* __restrict__ Xhi, unsigned short* __restrict__ Xlo,
    const unsigned char* __restrict__ mraw, unsigned char* __restrict__ mout) {
    const int bid = blockIdx.x;
    const int t = threadIdx.x;

    if (bid == 1216) {   // ---- mask canonicalizer ----
        __shared__ int s_not01, s_not0f;
        const unsigned int* w = (const unsigned int*)mraw;
        if (t == 0) { s_not01 = 0; s_not0f = 0; }
        __syncthreads();
        int not01 = 0, not0f = 0;
        for (int i = t; i < 2048; i += 256) {
            unsigned int v = w[i];
            if (v != 0u && v != 1u) not01 = 1;
            if (v != 0u && v != 0x3F800000u) not0f = 1;
        }
        if (not01) atomicOr(&s_not01, 1);
        if (not0f) atomicOr(&s_not0f, 1);
        __syncthreads();
        int wordTyped = (!s_not01) || (!s_not0f);
        for (int i = t; i < B_ * ML_; i += 256) {
            unsigned char mv;
            if (wordTyped) mv = (w[i] != 0u) ? 1 : 0;
            else           mv = mraw[i] ? 1 : 0;
            mout[i] = mv;
        }
        return;
    }

    const float* src; unsigned short *dh, *dl; size_t soff, doff;
    if (bid < 64) {
        src = (bid < 32) ? Wq : Wk;
        soff = (size_t)(bid & 31) * 4096;
        doff = ((bid < 32) ? 0 : 131072) + soff;
        dh = Whi; dl = Wlo;
    } else if (bid < 192) {
        src = query;  soff = (size_t)(bid - 64) * 4096;  doff = soff;
        dh = Xhi; dl = Xlo;
    } else {
        src = memory; soff = (size_t)(bid - 192) * 4096; doff = 524288 + soff;
        dh = Xhi; dl = Xlo;
    }
    soff += (size_t)t * 16; doff += (size_t)t * 16;

    unsigned hw[8], lw[8];
#pragma unroll
    for (int i = 0; i < 4; ++i) {
        float4 v = *(const float4*)(src + soff + i * 4);
        split4(v, hw[i * 2], hw[i * 2 + 1], lw[i * 2], lw[i * 2 + 1]);
    }
    *(uint4*)(dh + doff)     = make_uint4(hw[0], hw[1], hw[2], hw[3]);
    *(uint4*)(dh + doff + 8) = make_uint4(hw[4], hw[5], hw[6], hw[7]);
    *(uint4*)(dl + doff)     = make_uint4(lw[0], lw[1], lw[2], lw[3]);
    *(uint4*)(dl + doff + 8) = make_uint4(lw[4], lw[5], lw[6], lw[7]);
}

// ---------------------------------------------------------------------------
// Projection via bf16x3-split MFMA. Pure load+MFMA, NO LDS/barriers/VALU.
// R4 failure (counters): VGPR=60 proves the compiler collapsed the depth-2
// register pipeline (needs ~130 regs) into serial load->wait->use: MfmaUtil
// 5%, ~<1 outstanding load/wave, pure exposed L2/L3 latency. Fix:
//   * depth-4 prefetch (4 named sets; 16 chunks = 4 rounds)
//   * sched_barrier(0) after every load batch pins issue order -> compiler
//     cannot sink loads to their uses; 24-32 loads stay in flight per wave
//   * __launch_bounds__(256,2): 256-VGPR budget for ~190 live regs.
// Same split + same MFMA accumulation order as R2..R4 -> bit-identical out.
// Grid 576 x 256, XCD-chunked swizzle (576 = 8*72 exact).
// ---------------------------------------------------------------------------
__global__ __launch_bounds__(256, 2) void proj_kernel(
    const unsigned short* __restrict__ Xhi, const unsigned short* __restrict__ Xlo,
    const unsigned short* __restrict__ Whi, const unsigned short* __restrict__ Wlo,
    const float* __restrict__ bq, const float* __restrict__ bk,
    float* __restrict__ Eq, float* __restrict__ Ek) {
    const int bid = blockIdx.x;
    const int t = threadIdx.x;
    const int wk = (bid & 7) * 72 + (bid >> 3);
    const int nb = wk & 3;
    const int mb = wk >> 2;          // 0..143

    const bool isQ = (mb < 16);
    const int arow0 = mb * 64;                        // row in X planes (global)
    const int orow0 = isQ ? mb * 64 : mb * 64 - 1024; // row in output
    const float* bias = isQ ? bq : bk;
    float* out = isQ ? Eq : Ek;
    const int wrb = (isQ ? 0 : 256) + nb * 64;        // W-plane row base

    const int w  = t >> 6;
    const int wm = w >> 1, wn = w & 1;
    const int l  = t & 63;
    const int lr = l & 15;    // frag row/col within 16-tile
    const int lk = l >> 4;    // k-group (8 els) within 32-chunk

    const unsigned short* pah0 = Xhi + (size_t)(arow0 + wm * 32 +  0 + lr) * 512 + lk * 8;
    const unsigned short* pah1 = Xhi + (size_t)(arow0 + wm * 32 + 16 + lr) * 512 + lk * 8;
    const unsigned short* pal0 = Xlo + (size_t)(arow0 + wm * 32 +  0 + lr) * 512 + lk * 8;
    const unsigned short* pal1 = Xlo + (size_t)(arow0 + wm * 32 + 16 + lr) * 512 + lk * 8;
    const unsigned short* pbh0 = Whi + (size_t)(wrb + wn * 32 +  0 + lr) * 512 + lk * 8;
    const unsigned short* pbh1 = Whi + (size_t)(wrb + wn * 32 + 16 + lr) * 512 + lk * 8;
    const unsigned short* pbl0 = Wlo + (size_t)(wrb + wn * 32 +  0 + lr) * 512 + lk * 8;
    const unsigned short* pbl1 = Wlo + (size_t)(wrb + wn * 32 + 16 + lr) * 512 + lk * 8;

    f4acc acc[2][2];
#pragma unroll
    for (int mi = 0; mi < 2; ++mi)
#pragma unroll
        for (int ni = 0; ni < 2; ++ni)
            acc[mi][ni] = (f4acc){0.f, 0.f, 0.f, 0.f};

    uint4 s0ah0, s0ah1, s0al0, s0al1, s0bh0, s0bh1, s0bl0, s0bl1;
    uint4 s1ah0, s1ah1, s1al0, s1al1, s1bh0, s1bh1, s1bl0, s1bl1;
    uint4 s2ah0, s2ah1, s2al0, s2al1, s2bh0, s2bh1, s2bl0, s2bl1;
    uint4 s3ah0, s3ah1, s3al0, s3al1, s3bh0, s3bh1, s3bl0, s3bl1;

#define LDSET(P, c) do {                                              \
    P##ah0 = *(const uint4*)(pah0 + (size_t)(c) * 32);                \
    P##ah1 = *(const uint4*)(pah1 + (size_t)(c) * 32);                \
    P##al0 = *(const uint4*)(pal0 + (size_t)(c) * 32);                \
    P##al1 = *(const uint4*)(pal1 + (size_t)(c) * 32);                \
    P##bh0 = *(const uint4*)(pbh0 + (size_t)(c) * 32);                \
    P##bh1 = *(const uint4*)(pbh1 + (size_t)(c) * 32);                \
    P##bl0 = *(const uint4*)(pbl0 + (size_t)(c) * 32);                \
    P##bl1 = *(const uint4*)(pbl1 + (size_t)(c) * 32); } while (0)

#define COMPSET(P) do {                                               \
    bfrag ah[2], al[2], bh[2], bl[2];                                 \
    ah[0] = __builtin_bit_cast(bfrag, P##ah0);                        \
    ah[1] = __builtin_bit_cast(bfrag, P##ah1);                        \
    al[0] = __builtin_bit_cast(bfrag, P##al0);                        \
    al[1] = __builtin_bit_cast(bfrag, P##al1);                        \
    bh[0] = __builtin_bit_cast(bfrag, P##bh0);                        \
    bh[1] = __builtin_bit_cast(bfrag, P##bh1);                        \
    bl[0] = __builtin_bit_cast(bfrag, P##bl0);                        \
    bl[1] = __builtin_bit_cast(bfrag, P##bl1);                        \
    _Pragma("unroll")                                                 \
    for (int mi = 0; mi < 2; ++mi)                                    \
    _Pragma("unroll")                                                 \
    for (int ni = 0; ni < 2; ++ni) {                                  \
        acc[mi][ni] = __builtin_amdgcn_mfma_f32_16x16x32_bf16(        \
            ah[mi], bh[ni], acc[mi][ni], 0, 0, 0);                    \
        acc[mi][ni] = __builtin_amdgcn_mfma_f32_16x16x32_bf16(        \
            ah[mi], bl[ni], acc[mi][ni], 0, 0, 0);                    \
        acc[mi][ni] = __builtin_amdgcn_mfma_f32_16x16x32_bf16(        \
            al[mi], bh[ni], acc[mi][ni], 0, 0, 0);                    \
    } } while (0)

#define SB __builtin_amdgcn_sched_barrier(0)

    LDSET(s0, 0); LDSET(s1, 1); LDSET(s2, 2); LDSET(s3, 3);
    SB;
    COMPSET(s0); LDSET(s0, 4);  SB;
    COMPSET(s1); LDSET(s1, 5);  SB;
    COMPSET(s2); LDSET(s2, 6);  SB;
    COMPSET(s3); LDSET(s3, 7);  SB;
    COMPSET(s0); LDSET(s0, 8);  SB;
    COMPSET(s1); LDSET(s1, 9);  SB;
    COMPSET(s2); LDSET(s2, 10); SB;
    COMPSET(s3); LDSET(s3, 11); SB;
    COMPSET(s0); LDSET(s0, 12); SB;
    COMPSET(s1); LDSET(s1, 13); SB;
    COMPSET(s2); LDSET(s2, 14); SB;
    COMPSET(s3); LDSET(s3, 15); SB;
    COMPSET(s0);
    COMPSET(s1);
    COMPSET(s2);
    COMPSET(s3);
#undef LDSET
#undef COMPSET
#undef SB

    // epilogue: bias + exp2, dword stores (lanes 0-15 contiguous cols)
    const float SC = 2.885390081777926815f;   // 2*log2(e)
    float bcol[2];
#pragma unroll
    for (int ni = 0; ni < 2; ++ni) bcol[ni] = bias[nb * 64 + wn * 32 + ni * 16 + lr];

#pragma unroll
    for (int mi = 0; mi < 2; ++mi)
#pragma unroll
        for (int ni = 0; ni < 2; ++ni) {
            const int col = nb * 64 + wn * 32 + ni * 16 + lr;
#pragma unroll
            for (int r = 0; r < 4; ++r) {
                const int row = orow0 + wm * 32 + mi * 16 + lk * 4 + r;
                out[(size_t)row * 256 + col] =
                    __builtin_amdgcn_exp2f(SC * (acc[mi][ni][r] + bcol[ni]));
            }
        }
}

// ---------------------------------------------------------------------------
// logits: sr[b][q][m] = sum_h wl[h] / (Eq[b][q][h]*Ek[b][m][h] + 1)
// (tanh folded; exp precomputed). 4-way reciprocal grouping: 1 rcp per 4 h.
// LDS-FREE rewrite. R3 was LDS-port-bound (6 ds_read_b128/quad, 43 us);
// R4 kept barriers+low occupancy. Now: grid 2048 (b = bid&7 -> each XCD's
// L2 holds its 1 MB Ek slice), thread owns 1 m-row x 2 q-rows; Ek read
// per-lane from L2 (each 64B line fully consumed within its chunk); q/wl
// wave-uniform (scalar path). No LDS, no barriers; latency hidden by
// occupancy (launch_bounds(256,4), ~50 VGPR) x 2x VALU coverage.
// Per-output fma/rcp ordering identical to R3 -> bit-identical results.
// ---------------------------------------------------------------------------
__device__ __forceinline__ float qterm(const float4 k4, const float4 q4,
                                       const float4 w4, float acc) {
    float p0 = fmaf(k4.x, q4.x, 1.0f);
    float p1 = fmaf(k4.y, q4.y, 1.0f);
    float p2 = fmaf(k4.z, q4.z, 1.0f);
    float p3 = fmaf(k4.w, q4.w, 1.0f);
    float p01 = p0 * p1, p23 = p2 * p3;
    float n01 = fmaf(w4.y, p0, w4.x * p1);
    float n23 = fmaf(w4.w, p2, w4.z * p3);
    float Nm  = fmaf(n23, p01, n01 * p23);
    float P   = p01 * p23;
    return fmaf(Nm, __builtin_amdgcn_rcpf(P), acc);
}

__global__ __launch_bounds__(256, 4) void logits_kernel(
    const float* __restrict__ Eq, const float* __restrict__ Ek,
    const float* __restrict__ wl, float* __restrict__ sr) {
    const int bid = blockIdx.x;
    const int b  = bid & 7;          // XCD affinity: batch <-> XCD
    const int r  = bid >> 3;         // 0..255
    const int mt = r & 15;           // m tile of 64
    const int qt = r >> 4;           // q octet (0..15)
    const int tid = threadIdx.x;
    const int m  = tid & 63;
    const int qp = __builtin_amdgcn_readfirstlane(tid >> 6);  // 0..3, wave-uniform

    const float* kr = Ek + ((size_t)(b * ML_ + mt * 64 + m)) * H_;
    const float* q0 = Eq + ((size_t)(b * QL_ + qt * 8 + qp * 2)) * H_;
    const float* q1 = q0 + H_;

    float acc0 = 0.f, acc1 = 0.f;
#pragma unroll
    for (int c = 0; c < 16; ++c) {
        const int h0 = c * 16;
        float4 kA = *(const float4*)(kr + h0);
        float4 kB = *(const float4*)(kr + h0 + 4);
        float4 kC = *(const float4*)(kr + h0 + 8);
        float4 kD = *(const float4*)(kr + h0 + 12);

        float4 w4, qa, qb;
        w4 = *(const float4*)(wl + h0);
        qa = *(const float4*)(q0 + h0);
        qb = *(const float4*)(q1 + h0);
        acc0 = qterm(kA, qa, w4, acc0);
        acc1 = qterm(kA, qb, w4, acc1);

        w4 = *(const float4*)(wl + h0 + 4);
        qa = *(const float4*)(q0 + h0 + 4);
        qb = *(const float4*)(q1 + h0 + 4);
        acc0 = qterm(kB, qa, w4, acc0);
        acc1 = qterm(kB, qb, w4, acc1);

        w4 = *(const float4*)(wl + h0 + 8);
        qa = *(const float4*)(q0 + h0 + 8);
        qb = *(const float4*)(q1 + h0 + 8);
        acc0 = qterm(kC, qa, w4, acc0);
        acc1 = qterm(kC, qb, w4, acc1);

        w4 = *(const float4*)(wl + h0 + 12);
        qa = *(const float4*)(q0 + h0 + 12);
        qb = *(const float4*)(q1 + h0 + 12);
        acc0 = qterm(kD, qa, w4, acc0);
        acc1 = qterm(kD, qb, w4, acc1);
    }

    const size_t ro = ((size_t)(b * QL_ + qt * 8 + qp * 2)) * ML_ + mt * 64 + m;
    sr[ro]       = acc0;
    sr[ro + ML_] = acc1;
}

// ---------------------------------------------------------------------------
// In-place masked softmax (unchanged). logits_eff = -2*sr (shift-invariant).
// ---------------------------------------------------------------------------
__global__ __launch_bounds__(256) void softmax_kernel(
    float* __restrict__ wrow_io, const unsigned char* __restrict__ mv) {
    const int row = blockIdx.x;
    const int b = row >> 7;
    const int tid = threadIdx.x;
    float* srow = wrow_io + (size_t)row * ML_;
    const unsigned char* mrow = mv + b * ML_;
    __shared__ float red[4];

    float4 s4 = *(const float4*)(srow + tid * 4);
    uchar4 m4 = *(const uchar4*)(mrow + tid * 4);
    float l[4];
    l[0] = m4.x ? -1e18f : -2.0f * s4.x;
    l[1] = m4.y ? -1e18f : -2.0f * s4.y;
    l[2] = m4.z ? -1e18f : -2.0f * s4.z;
    l[3] = m4.w ? -1e18f : -2.0f * s4.w;

    float mx = fmaxf(fmaxf(l[0], l[1]), fmaxf(l[2], l[3]));
#pragma unroll
    for (int off = 32; off >= 1; off >>= 1)
        mx = fmaxf(mx, __shfl_xor(mx, off));
    if ((tid & 63) == 0) red[tid >> 6] = mx;
    __syncthreads();
    mx = fmaxf(fmaxf(red[0], red[1]), fmaxf(red[2], red[3]));
    __syncthreads();

    const float L2E = 1.44269504088896340736f;
    float e[4], s = 0.f;
#pragma unroll
    for (int i = 0; i < 4; ++i) {
        e[i] = __builtin_amdgcn_exp2f((l[i] - mx) * L2E);
        s += e[i];
    }
#pragma unroll
    for (int off = 32; off >= 1; off >>= 1)
        s += __shfl_xor(s, off);
    if ((tid & 63) == 0) red[tid >> 6] = s;
    __syncthreads();
    s = (red[0] + red[1]) + (red[2] + red[3]);
    float inv = __builtin_amdgcn_rcpf(s);
    float4 o = make_float4(e[0] * inv, e[1] * inv, e[2] * inv, e[3] * inv);
    *(float4*)(srow + tid * 4) = o;
}

// ---------------------------------------------------------------------------
// attns[b] = W[b] (128x1024) @ M[b] (1024x512). LDS-tiled GEMM (unchanged).
// ---------------------------------------------------------------------------
__global__ __launch_bounds__(256) void attn_out_kernel(
    const float* __restrict__ wgt, const float* __restrict__ mem,
    float* __restrict__ out) {
    const int bid = blockIdx.x;
    const int b  = bid & 7;
    const int j2 = bid >> 3;
    const int mt = j2 & 3;
    const int nt = j2 >> 2;
    const int t = threadIdx.x;
    __shared__ float As[32][34];
    __shared__ float Bs[32][64];

    const int ar = t >> 3, ac = (t & 7) << 2;
    const int br = t >> 4, bc = (t & 15) << 2;
    const float* Ap = wgt + ((size_t)(b * QL_ + mt * 32 + ar)) * ML_ + ac;
    const float* Bp = mem + ((size_t)(b * ML_ + br)) * KS_ + nt * 64 + bc;

    const int tx = t & 15, ty = t >> 4;
    float acc0[4] = {0.f, 0.f, 0.f, 0.f};
    float acc1[4] = {0.f, 0.f, 0.f, 0.f};

    float4 apre = *(const float4*)(Ap);
    float4 bpre0 = *(const float4*)(Bp);
    float4 bpre1 = *(const float4*)(Bp + (size_t)16 * KS_);

    for (int k0 = 0; k0 < ML_; k0 += 32) {
        __syncthreads();
        As[ac + 0][ar] = apre.x; As[ac + 1][ar] = apre.y;
        As[ac + 2][ar] = apre.z; As[ac + 3][ar] = apre.w;
        *(float4*)(&Bs[br][bc])      = bpre0;
        *(float4*)(&Bs[br + 16][bc]) = bpre1;
        __syncthreads();
        if (k0 + 32 < ML_) {
            apre  = *(const float4*)(Ap + k0 + 32);
            bpre0 = *(const float4*)(Bp + (size_t)(k0 + 32) * KS_);
            bpre1 = *(const float4*)(Bp + (size_t)(k0 + 48) * KS_);
        }
#pragma unroll
        for (int kk = 0; kk < 32; ++kk) {
            float2 a2 = *(const float2*)(&As[kk][ty * 2]);
            float4 b4 = *(const float4*)(&Bs[kk][tx * 4]);
            acc0[0] = fmaf(a2.x, b4.x, acc0[0]);
            acc0[1] = fmaf(a2.x, b4.y, acc0[1]);
            acc0[2] = fmaf(a2.x, b4.z, acc0[2]);
            acc0[3] = fmaf(a2.x, b4.w, acc0[3]);
            acc1[0] = fmaf(a2.y, b4.x, acc1[0]);
            acc1[1] = fmaf(a2.y, b4.y, acc1[1]);
            acc1[2] = fmaf(a2.y, b4.z, acc1[2]);
            acc1[3] = fmaf(a2.y, b4.w, acc1[3]);
        }
    }
    size_t orow = ((size_t)(b * QL_ + mt * 32 + ty * 2)) * KS_ + nt * 64 + tx * 4;
    *(float4*)(out + orow)       = make_float4(acc0[0], acc0[1], acc0[2], acc0[3]);
    *(float4*)(out + orow + KS_) = make_float4(acc1[0], acc1[1], acc1[2], acc1[3]);
}

extern "C" void kernel_launch(void* const* d_in, const int* in_sizes, int n_in,
                              void* d_out, int out_size, void* d_ws, size_t ws_size,
                              hipStream_t stream) {
    const float* query  = (const float*)d_in[0];
    const float* memory = (const float*)d_in[1];
    const unsigned char* mask = (const unsigned char*)d_in[2];
    const float* Wq = (const float*)d_in[3];
    const float* bq = (const float*)d_in[4];
    const float* Wk = (const float*)d_in[5];
    const float* bk = (const float*)d_in[6];
    const float* wl = (const float*)d_in[7];
    // d_in[8] (bl) cancels under softmax shift-invariance; not read.

    float* ws = (float*)d_ws;
    float* Eq = ws + QP_OFF;
    float* Ek = ws + KP_OFF;
    unsigned char* mcan = (unsigned char*)(ws + MASK_OFF);
    unsigned short* Whi = (unsigned short*)(ws + WH_OFF);
    unsigned short* Wlo = (unsigned short*)(ws + WL_OFF);
    unsigned short* Xhi = (unsigned short*)(ws + XH_OFF);
    unsigned short* Xlo = (unsigned short*)(ws + XL_OFF);

    float* attns = (float*)d_out;                      // [B][QL][KS]
    float* wout  = (float*)d_out + B_ * QL_ * KS_;     // [B][QL][ML] (also sr scratch)

    prep_kernel<<<dim3(1217), dim3(256), 0, stream>>>(query, memory, Wq, Wk,
                                                      Whi, Wlo, Xhi, Xlo, mask, mcan);
    proj_kernel<<<dim3(576), dim3(256), 0, stream>>>(Xhi, Xlo, Whi, Wlo,
                                                     bq, bk, Eq, Ek);
    logits_kernel<<<dim3(2048), dim3(256), 0, stream>>>(Eq, Ek, wl, wout);
    softmax_kernel<<<dim3(B_ * QL_), dim3(256), 0, stream>>>(wout, mcan);
    attn_out_kernel<<<dim3(256), dim3(256), 0, stream>>>(wout, memory, attns);
}

// Round 6
// 165.958 us; speedup vs baseline: 1.4000x; 1.4000x over previous
//
#include <hip/hip_runtime.h>

#define B_  8
#define QL_ 128
#define ML_ 1024
#define KS_ 512
#define H_  256

// ws layout (floats):
//   Eq = exp2(2log2e*qproj): [B][QL][H]   @ 0        (262144)
//   Ek = exp2(2log2e*kproj): [B][ML][H]   @ 262144   (2097152)
//   mask canonical uint8 [B*ML]           @ 2359296  (2048 float slots)
//   Whi bf16 [512][512]                   @ 2361344  (131072)
//   Wlo bf16 [512][512]                   @ 2492416  (131072)
//   MThi bf16 [8][512][1024] (memory^T)   @ 2623488  (2097152)
//   MTlo bf16 [8][512][1024]              @ 4720640  (2097152)
//   Wbhi bf16 [8][128][1024] (weights)    @ 6817792  (524288)
//   Wblo bf16 [8][128][1024]              @ 7342080  (524288)
#define QP_OFF 0
#define KP_OFF 262144
#define MASK_OFF 2359296
#define WH_OFF 2361344
#define WL_OFF 2492416
#define MT_H_OFF 2623488
#define MT_L_OFF 4720640
#define WB_H_OFF 6817792
#define WB_L_OFF 7342080

typedef __attribute__((ext_vector_type(8))) short bfrag;   // 8 bf16 (4 VGPR)
typedef __attribute__((ext_vector_type(4))) float f4acc;   // MFMA acc

// fp32 -> (hi,lo) bf16 split. hi = truncation (residual <= 2^-8|x|, captured
// exactly by fp32 subtract); lo = RNE of residual (final err <= 2^-17|x|).
__device__ __forceinline__ void split1(float v, unsigned& h, unsigned& lo) {
    unsigned u  = __float_as_uint(v);
    unsigned hb = u & 0xFFFF0000u;
    float    lf = v - __uint_as_float(hb);           // exact
    unsigned ul = __float_as_uint(lf);
    unsigned lr = ul + 0x7FFFu + ((ul >> 16) & 1u);  // RNE
    h  = u >> 16;
    lo = lr >> 16;
}

__device__ __forceinline__ void split4(const float4& a, unsigned& h01, unsigned& h23,
                                       unsigned& l01, unsigned& l23) {
    unsigned h[4], l[4];
    split1(a.x, h[0], l[0]); split1(a.y, h[1], l[1]);
    split1(a.z, h[2], l[2]); split1(a.w, h[3], l[3]);
    h01 = h[0] | (h[1] << 16); h23 = h[2] | (h[3] << 16);
    l01 = l[0] | (l[1] << 16); l23 = l[2] | (l[3] << 16);
}

// ---------------------------------------------------------------------------
// Prep kernel, grid 1089 x 256:
//   bid 0..63   : W split (Wq -> rows 0..255, Wk -> rows 256..511 of Whi/Wlo)
//   bid 64..1087: memory transpose-split -> MThi/MTlo[b][s][m] (B-operand for
//                 the MFMA attn_out: B-frag needs k(=m)-contiguous per col s)
//   bid 1088    : mask canonicalizer
// ---------------------------------------------------------------------------
__global__ __launch_bounds__(256) void prep_kernel(
    const float* __restrict__ memory,
    const float* __restrict__ Wq, const float* __restrict__ Wk,
    unsigned short* __restrict__ Whi, unsigned short* __restrict__ Wlo,
    unsigned short* __restrict__ MThi, unsigned short* __restrict__ MTlo,
    const unsigned char* __restrict__ mraw, unsigned char* __restrict__ mout) {
    const int bid = blockIdx.x;
    const int t = threadIdx.x;

    if (bid == 1088) {   // ---- mask canonicalizer ----
        __shared__ int s_not01, s_not0f;
        const unsigned int* w = (const unsigned int*)mraw;
        if (t == 0) { s_not01 = 0; s_not0f = 0; }
        __syncthreads();
        int not01 = 0, not0f = 0;
        for (int i = t; i < 2048; i += 256) {
            unsigned int v = w[i];
            if (v != 0u && v != 1u) not01 = 1;
            if (v != 0u && v != 0x3F800000u) not0f = 1;
        }
        if (not01) atomicOr(&s_not01, 1);
        if (not0f) atomicOr(&s_not0f, 1);
        __syncthreads();
        int wordTyped = (!s_not01) || (!s_not0f);
        for (int i = t; i < B_ * ML_; i += 256) {
            unsigned char mv;
            if (wordTyped) mv = (w[i] != 0u) ? 1 : 0;
            else           mv = mraw[i] ? 1 : 0;
            mout[i] = mv;
        }
        return;
    }

    if (bid < 64) {      // ---- W split (R3-proven) ----
        const float* src = (bid < 32) ? Wq : Wk;
        size_t loff = (size_t)(bid & 31) * 4096 + (size_t)t * 16;
        size_t doff = ((bid < 32) ? 0 : 131072) + loff;
        unsigned hw[8], lw[8];
#pragma unroll
        for (int i = 0; i < 4; ++i) {
            float4 v = *(const float4*)(src + loff + i * 4);
            split4(v, hw[i * 2], hw[i * 2 + 1], lw[i * 2], lw[i * 2 + 1]);
        }
        *(uint4*)(Whi + doff)     = make_uint4(hw[0], hw[1], hw[2], hw[3]);
        *(uint4*)(Whi + doff + 8) = make_uint4(hw[4], hw[5], hw[6], hw[7]);
        *(uint4*)(Wlo + doff)     = make_uint4(lw[0], lw[1], lw[2], lw[3]);
        *(uint4*)(Wlo + doff + 8) = make_uint4(lw[4], lw[5], lw[6], lw[7]);
        return;
    }

    // ---- memory transpose-split: 64x64 fp32 tile via LDS ----
    const int idx = bid - 64;        // 0..1023
    const int b  = idx >> 7;         // batch
    const int r  = idx & 127;
    const int mt = r >> 3;           // m tile (16 of 64 rows)
    const int st = r & 7;            // s tile (8 of 64 cols)
    __shared__ float T[64][68];      // 68: float4-aligned, odd-ish bank stride

    const int i  = t >> 2, jb = (t & 3) << 4;
    const float* mp = memory + ((size_t)(b * ML_ + mt * 64 + i)) * KS_ + st * 64 + jb;
#pragma unroll
    for (int q = 0; q < 4; ++q)
        *(float4*)(&T[i][jb + q * 4]) = *(const float4*)(mp + q * 4);
    __syncthreads();

    const int s = t >> 2, mb = (t & 3) << 4;
    unsigned hh[16], ll[16];
#pragma unroll
    for (int e = 0; e < 16; ++e) split1(T[mb + e][s], hh[e], ll[e]);
    unsigned hp[8], lp[8];
#pragma unroll
    for (int e = 0; e < 8; ++e) {
        hp[e] = hh[2 * e] | (hh[2 * e + 1] << 16);
        lp[e] = ll[2 * e] | (ll[2 * e + 1] << 16);
    }
    const size_t doff = ((size_t)(b * KS_ + st * 64 + s)) * ML_ + mt * 64 + mb;
    *(uint4*)(MThi + doff)     = make_uint4(hp[0], hp[1], hp[2], hp[3]);
    *(uint4*)(MThi + doff + 8) = make_uint4(hp[4], hp[5], hp[6], hp[7]);
    *(uint4*)(MTlo + doff)     = make_uint4(lp[0], lp[1], lp[2], lp[3]);
    *(uint4*)(MTlo + doff + 8) = make_uint4(lp[4], lp[5], lp[6], lp[7]);
}

// ---------------------------------------------------------------------------
// Projection via bf16x3-split MFMA — R3 version VERBATIM (best measured:
// all proj dispatches < 42.1 us in R3's profile; R4's no-LDS = 47, R5's
// sched_barrier = ~60+). LDS-staged A-split + pre-split W, ping-pong,
// register prefetch, 576 blocks.
// ---------------------------------------------------------------------------
__global__ __launch_bounds__(256) void proj_kernel(
    const float* __restrict__ query, const float* __restrict__ memory,
    const unsigned short* __restrict__ Whi, const unsigned short* __restrict__ Wlo,
    const float* __restrict__ bq, const float* __restrict__ bk,
    float* __restrict__ Eq, float* __restrict__ Ek) {
    const int bid = blockIdx.x;
    const int t = threadIdx.x;
    const int nb = bid & 1;          // n half: cols [nb*128, nb*128+128)
    const int mb = bid >> 1;         // m tile of 32 rows (0..287)

    const float *X, *bias; float* out; int row0, wbase0;
    if (mb < 32) { X = query;  bias = bq; out = Eq; row0 = mb * 32;        wbase0 = 0; }
    else         { X = memory; bias = bk; out = Ek; row0 = (mb - 32) * 32; wbase0 = 256; }

    const int w  = t >> 6;    // wave id -> n sub-block of 32
    const int l  = t & 63;
    const int lr = l & 15;    // frag row/col within 16-tile
    const int lk = l >> 4;    // k-group (8 els) within 32-chunk

    const int arow = t >> 3;          // 0..31
    const int acol = (t & 7) << 2;    // 0,4,..,28
    const float* Xp = X + (size_t)(row0 + arow) * 512 + acol;
    __shared__ unsigned int AH[2][32][16];
    __shared__ unsigned int AL[2][32][16];
    const int wg  = ((t & 7) >> 1) ^ ((arow >> 1) & 3);  // swizzled write group
    const int wwo = ((t & 7) & 1) << 1;                  // word pair within group

    const int wrow0 = wbase0 + nb * 128 + w * 32;
    const unsigned short* bhP0 = Whi + (size_t)(wrow0 + 0 * 16 + lr) * 512 + lk * 8;
    const unsigned short* bhP1 = Whi + (size_t)(wrow0 + 1 * 16 + lr) * 512 + lk * 8;
    const unsigned short* blP0 = Wlo + (size_t)(wrow0 + 0 * 16 + lr) * 512 + lk * 8;
    const unsigned short* blP1 = Wlo + (size_t)(wrow0 + 1 * 16 + lr) * 512 + lk * 8;

    f4acc acc[2][2];
#pragma unroll
    for (int mi = 0; mi < 2; ++mi)
#pragma unroll
        for (int ni = 0; ni < 2; ++ni)
            acc[mi][ni] = (f4acc){0.f, 0.f, 0.f, 0.f};

#define WRA(P, XA) do {                                               \
    unsigned h01, h23, l01, l23;                                      \
    split4(XA, h01, h23, l01, l23);                                   \
    unsigned int* dh = &AH[P][arow][wg * 4 + wwo];                    \
    unsigned int* dl = &AL[P][arow][wg * 4 + wwo];                    \
    dh[0] = h01; dh[1] = h23; dl[0] = l01; dl[1] = l23; } while (0)

#define LDB(BH0, BH1, BL0, BL1, c) do {                               \
    BH0 = *(const uint4*)(bhP0 + (size_t)(c) * 32);                   \
    BH1 = *(const uint4*)(bhP1 + (size_t)(c) * 32);                   \
    BL0 = *(const uint4*)(blP0 + (size_t)(c) * 32);                   \
    BL1 = *(const uint4*)(blP1 + (size_t)(c) * 32); } while (0)

#define COMP(P, BH0, BH1, BL0, BL1) do {                              \
    bfrag ah[2], al[2];                                               \
    _Pragma("unroll")                                                 \
    for (int mi = 0; mi < 2; ++mi) {                                  \
        int ra = mi * 16 + lr;                                        \
        int g4 = (lk ^ ((ra >> 1) & 3)) * 4;                          \
        ah[mi] = *(const bfrag*)&AH[P][ra][g4];                       \
        al[mi] = *(const bfrag*)&AL[P][ra][g4];                       \
    }                                                                 \
    bfrag bh[2], bl[2];                                               \
    bh[0] = __builtin_bit_cast(bfrag, BH0);                           \
    bh[1] = __builtin_bit_cast(bfrag, BH1);                           \
    bl[0] = __builtin_bit_cast(bfrag, BL0);                           \
    bl[1] = __builtin_bit_cast(bfrag, BL1);                           \
    _Pragma("unroll")                                                 \
    for (int mi = 0; mi < 2; ++mi)                                    \
    _Pragma("unroll")                                                 \
    for (int ni = 0; ni < 2; ++ni) {                                  \
        acc[mi][ni] = __builtin_amdgcn_mfma_f32_16x16x32_bf16(        \
            ah[mi], bh[ni], acc[mi][ni], 0, 0, 0);                    \
        acc[mi][ni] = __builtin_amdgcn_mfma_f32_16x16x32_bf16(        \
            ah[mi], bl[ni], acc[mi][ni], 0, 0, 0);                    \
        acc[mi][ni] = __builtin_amdgcn_mfma_f32_16x16x32_bf16(        \
            al[mi], bh[ni], acc[mi][ni], 0, 0, 0);                    \
    } } while (0)

    float4 xa0 = *(const float4*)(Xp);
    uint4 bh00, bh01, bl00, bl01;
    LDB(bh00, bh01, bl00, bl01, 0);
    float4 xa1 = *(const float4*)(Xp + 32);
    uint4 bh10, bh11, bl10, bl11;
    LDB(bh10, bh11, bl10, bl11, 1);
    WRA(0, xa0);
    __syncthreads();

    for (int c2 = 0; c2 < 8; ++c2) {
        WRA(1, xa1);
        if (c2 < 7) xa0 = *(const float4*)(Xp + (2 * c2 + 2) * 32);
        COMP(0, bh00, bh01, bl00, bl01);
        if (c2 < 7) LDB(bh00, bh01, bl00, bl01, 2 * c2 + 2);
        __syncthreads();
        if (c2 < 7) WRA(0, xa0);
        COMP(1, bh10, bh11, bl10, bl11);
        if (c2 < 7) {
            xa1 = *(const float4*)(Xp + (2 * c2 + 3) * 32);
            LDB(bh10, bh11, bl10, bl11, 2 * c2 + 3);
        }
        __syncthreads();
    }
#undef WRA
#undef LDB
#undef COMP

    const float SC = 2.885390081777926815f;   // 2*log2(e)
    float bcol[2];
#pragma unroll
    for (int ni = 0; ni < 2; ++ni) bcol[ni] = bias[nb * 128 + w * 32 + ni * 16 + lr];

#pragma unroll
    for (int mi = 0; mi < 2; ++mi)
#pragma unroll
        for (int ni = 0; ni < 2; ++ni) {
            const int col = nb * 128 + w * 32 + ni * 16 + lr;
#pragma unroll
            for (int r = 0; r < 4; ++r) {
                const int row = row0 + mi * 16 + lk * 4 + r;
                out[(size_t)row * 256 + col] =
                    __builtin_amdgcn_exp2f(SC * (acc[mi][ni][r] + bcol[ni]));
            }
        }
}

// ---------------------------------------------------------------------------
// logits — R3 version VERBATIM (best measured: 43 us). LDS staging of Ek is
// REQUIRED: per-lane-row global reads (R5) cost 64 lines/instr -> 2 GB L2
// traffic -> 65 us. Ping-pong kq, 1 barrier/chunk, uniform q4/w4 loads.
// ---------------------------------------------------------------------------
__global__ __launch_bounds__(256) void logits_kernel(
    const float* __restrict__ Eq, const float* __restrict__ Ek,
    const float* __restrict__ wl, float* __restrict__ sr) {
    const int bid = blockIdx.x;
    const int b  = bid & 7;
    const int r2 = bid >> 3;
    const int mt = r2 & 7;      // m tile of 128
    const int qt = r2 >> 3;     // q octet
    const int tid = threadIdx.x;
    const int m  = tid & 127;
    const int qh = __builtin_amdgcn_readfirstlane(tid >> 7);  // wave-uniform

    __shared__ float kq[2][4][128][4];   // [buf][h-quad][m][4]

    const float* qpb = Eq + ((size_t)(b * QL_ + qt * 8 + qh * 4)) * H_;
    const float* kpb = Ek + ((size_t)(b * ML_ + mt * 128)) * H_;

    const int srow = tid & 127;
    const int sq2  = tid >> 7;
    const float* kst = kpb + (size_t)srow * H_ + 8 * sq2;

    float4 a0 = *(const float4*)(kst);
    float4 a1 = *(const float4*)(kst + 4);
    *(float4*)(&kq[0][2 * sq2 + 0][srow][0]) = a0;
    *(float4*)(&kq[0][2 * sq2 + 1][srow][0]) = a1;
    a0 = *(const float4*)(kst + 16);
    a1 = *(const float4*)(kst + 20);
    __syncthreads();

    float acc[4] = {0.f, 0.f, 0.f, 0.f};

    for (int c = 0; c < 16; ++c) {
        const int cb = c & 1;
        if (c < 15) {
            *(float4*)(&kq[cb ^ 1][2 * sq2 + 0][srow][0]) = a0;
            *(float4*)(&kq[cb ^ 1][2 * sq2 + 1][srow][0]) = a1;
            if (c < 14) {
                a0 = *(const float4*)(kst + (c + 2) * 16);
                a1 = *(const float4*)(kst + (c + 2) * 16 + 4);
            }
        }
        const int h0 = c * 16;
#pragma unroll
        for (int quad = 0; quad < 4; ++quad) {
            float4 k4 = *(const float4*)(&kq[cb][quad][m][0]);
            float4 w4 = *(const float4*)(wl + h0 + quad * 4);
#pragma unroll
            for (int j2 = 0; j2 < 4; ++j2) {
                float4 q4 = *(const float4*)(qpb + (size_t)j2 * H_ + h0 + quad * 4);
                float p0 = fmaf(k4.x, q4.x, 1.0f);
                float p1 = fmaf(k4.y, q4.y, 1.0f);
                float p2 = fmaf(k4.z, q4.z, 1.0f);
                float p3 = fmaf(k4.w, q4.w, 1.0f);
                float p01 = p0 * p1, p23 = p2 * p3;
                float n01 = fmaf(w4.y, p0, w4.x * p1);
                float n23 = fmaf(w4.w, p2, w4.z * p3);
                float Nm  = fmaf(n23, p01, n01 * p23);
                float P   = p01 * p23;
                acc[j2] = fmaf(Nm, __builtin_amdgcn_rcpf(P), acc[j2]);
            }
        }
        __syncthreads();
    }
#pragma unroll
    for (int j2 = 0; j2 < 4; ++j2)
        sr[((size_t)(b * QL_ + qt * 8 + qh * 4 + j2)) * ML_ + mt * 128 + m] = acc[j2];
}

// ---------------------------------------------------------------------------
// In-place masked softmax + bf16 hi/lo split of weights for the MFMA
// attn_out (A-operand). logits_eff = -2*sr (shift-invariant).
// ---------------------------------------------------------------------------
__global__ __launch_bounds__(256) void softmax_kernel(
    float* __restrict__ wrow_io, const unsigned char* __restrict__ mv,
    unsigned short* __restrict__ Wbhi, unsigned short* __restrict__ Wblo) {
    const int row = blockIdx.x;
    const int b = row >> 7;
    const int tid = threadIdx.x;
    float* srow = wrow_io + (size_t)row * ML_;
    const unsigned char* mrow = mv + b * ML_;
    __shared__ float red[4];

    float4 s4 = *(const float4*)(srow + tid * 4);
    uchar4 m4 = *(const uchar4*)(mrow + tid * 4);
    float l[4];
    l[0] = m4.x ? -1e18f : -2.0f * s4.x;
    l[1] = m4.y ? -1e18f : -2.0f * s4.y;
    l[2] = m4.z ? -1e18f : -2.0f * s4.z;
    l[3] = m4.w ? -1e18f : -2.0f * s4.w;

    float mx = fmaxf(fmaxf(l[0], l[1]), fmaxf(l[2], l[3]));
#pragma unroll
    for (int off = 32; off >= 1; off >>= 1)
        mx = fmaxf(mx, __shfl_xor(mx, off));
    if ((tid & 63) == 0) red[tid >> 6] = mx;
    __syncthreads();
    mx = fmaxf(fmaxf(red[0], red[1]), fmaxf(red[2], red[3]));
    __syncthreads();

    const float L2E = 1.44269504088896340736f;
    float e[4], s = 0.f;
#pragma unroll
    for (int i = 0; i < 4; ++i) {
        e[i] = __builtin_amdgcn_exp2f((l[i] - mx) * L2E);
        s += e[i];
    }
#pragma unroll
    for (int off = 32; off >= 1; off >>= 1)
        s += __shfl_xor(s, off);
    if ((tid & 63) == 0) red[tid >> 6] = s;
    __syncthreads();
    s = (red[0] + red[1]) + (red[2] + red[3]);
    float inv = __builtin_amdgcn_rcpf(s);
    float4 o = make_float4(e[0] * inv, e[1] * inv, e[2] * inv, e[3] * inv);
    *(float4*)(srow + tid * 4) = o;

    unsigned h01, h23, l01, l23;
    split4(o, h01, h23, l01, l23);
    *(uint2*)(Wbhi + (size_t)row * ML_ + tid * 4) = make_uint2(h01, h23);
    *(uint2*)(Wblo + (size_t)row * ML_ + tid * 4) = make_uint2(l01, l23);
}

// ---------------------------------------------------------------------------
// attns[b] = weights[b] (128x1024) @ memory[b] (1024x512) via bf16x3 MFMA.
// Old fp32 version: 256 blocks = 1 wave/SIMD, LDS-heavy -> the same
// low-occupancy-latency signature that cost proj 52us in R0 (never directly
// measured; est 20-60us). New: A = Wbhi/Wblo (softmax split), B = MThi/MTlo
// (memory^T from prep; B-frag needs k(=m)-contiguous per output col s).
// Grid 512 x 256 (2 blocks/CU, 8 waves/CU): b=bid&7 (XCD affinity),
// block = 16m x 64n, 4 waves each 16m x 16n (1 frag, acc=4 VGPR), BK=64.
// G4 XOR-swizzle (kchunk ^= row&7) on both LDS write+read: conflict-free.
// Single-barrier ping-pong + depth-1.5 register prefetch (R3-logits-proven).
// ---------------------------------------------------------------------------
__global__ __launch_bounds__(256) void attn_out_kernel(
    const unsigned short* __restrict__ Wbhi, const unsigned short* __restrict__ Wblo,
    const unsigned short* __restrict__ MThi, const unsigned short* __restrict__ MTlo,
    float* __restrict__ out) {
    const int bid = blockIdx.x;
    const int b  = bid & 7;
    const int r  = bid >> 3;          // 0..63
    const int mt = r & 7;             // m tile of 16
    const int nt = r >> 3;            // n tile of 64
    const int t = threadIdx.x;
    const int w  = t >> 6;
    const int l  = t & 63;
    const int lr = l & 15, lk = l >> 4;

    __shared__ unsigned short As[2][16][2][64];   // [buf][row][plane][k]
    __shared__ unsigned short Bs[2][64][2][64];

    // staging maps (reg -> LDS, swizzled)
    const int pa  = t >> 7;                 // plane (hi/lo)
    const int ar  = (t >> 3) & 15;          // A row
    const int acq = t & 7;                  // A k-chunk (8 shorts)
    const unsigned short* asrc = (pa ? Wblo : Wbhi)
        + ((size_t)(b * QL_ + mt * 16 + ar)) * ML_ + acq * 8;
    const int aws = (acq ^ (ar & 7)) * 8;

    const int pb  = t >> 7;
    const int br  = (t & 127) >> 1;         // B row 0..63
    const int bq0 = (t & 1) * 4;            // first of 4 k-chunks
    const unsigned short* bsrc = (pb ? MTlo : MThi)
        + ((size_t)(b * KS_ + nt * 64 + br)) * ML_ + bq0 * 8;
    int bws[4];
#pragma unroll
    for (int i2 = 0; i2 < 4; ++i2) bws[i2] = ((bq0 + i2) ^ (br & 7)) * 8;

    f4acc acc = (f4acc){0.f, 0.f, 0.f, 0.f};

    uint4 g0a, g0b0, g0b1, g0b2, g0b3;
    uint4 g1a, g1b0, g1b1, g1b2, g1b3;

#define LOADG(G, c) do {                                                  \
    G##a  = *(const uint4*)(asrc + (size_t)(c) * 64);                     \
    G##b0 = *(const uint4*)(bsrc + (size_t)(c) * 64);                     \
    G##b1 = *(const uint4*)(bsrc + (size_t)(c) * 64 + 8);                 \
    G##b2 = *(const uint4*)(bsrc + (size_t)(c) * 64 + 16);                \
    G##b3 = *(const uint4*)(bsrc + (size_t)(c) * 64 + 24); } while (0)

#define WRITEB(P, G) do {                                                 \
    *(uint4*)(&As[P][ar][pa][aws])    = G##a;                             \
    *(uint4*)(&Bs[P][br][pb][bws[0]]) = G##b0;                            \
    *(uint4*)(&Bs[P][br][pb][bws[1]]) = G##b1;                            \
    *(uint4*)(&Bs[P][br][pb][bws[2]]) = G##b2;                            \
    *(uint4*)(&Bs[P][br][pb][bws[3]]) = G##b3; } while (0)

#define COMPUTE(P) do {                                                   \
    _Pragma("unroll")                                                     \
    for (int ks = 0; ks < 2; ++ks) {                                      \
        const int k8 = (ks * 4 + lk) ^ (lr & 7);                          \
        bfrag ah = *(const bfrag*)&As[P][lr][0][k8 * 8];                  \
        bfrag al = *(const bfrag*)&As[P][lr][1][k8 * 8];                  \
        bfrag bh = *(const bfrag*)&Bs[P][w * 16 + lr][0][k8 * 8];         \
        bfrag bl = *(const bfrag*)&Bs[P][w * 16 + lr][1][k8 * 8];         \
        acc = __builtin_amdgcn_mfma_f32_16x16x32_bf16(ah, bh, acc, 0,0,0);\
        acc = __builtin_amdgcn_mfma_f32_16x16x32_bf16(ah, bl, acc, 0,0,0);\
        acc = __builtin_amdgcn_mfma_f32_16x16x32_bf16(al, bh, acc, 0,0,0);\
    } } while (0)

    LOADG(g0, 0);
    WRITEB(0, g0);
    LOADG(g1, 1);
    __syncthreads();

#pragma unroll
    for (int c = 0; c < 16; ++c) {
        if (c + 1 < 16) {
            if ((c + 1) & 1) WRITEB(1, g1); else WRITEB(0, g0);
        }
        if (c + 2 < 16) {
            if (c & 1) LOADG(g1, c + 2); else LOADG(g0, c + 2);
        }
        COMPUTE(c & 1);
        __syncthreads();
    }
#undef LOADG
#undef WRITEB
#undef COMPUTE

    const int col = nt * 64 + w * 16 + lr;
#pragma unroll
    for (int rr = 0; rr < 4; ++rr) {
        const int row = mt * 16 + lk * 4 + rr;
        out[((size_t)(b * QL_ + row)) * KS_ + col] = acc[rr];
    }
}

extern "C" void kernel_launch(void* const* d_in, const int* in_sizes, int n_in,
                              void* d_out, int out_size, void* d_ws, size_t ws_size,
                              hipStream_t stream) {
    const float* query  = (const float*)d_in[0];
    const float* memory = (const float*)d_in[1];
    const unsigned char* mask = (const unsigned char*)d_in[2];
    const float* Wq = (const float*)d_in[3];
    const float* bq = (const float*)d_in[4];
    const float* Wk = (const float*)d_in[5];
    const float* bk = (const float*)d_in[6];
    const float* wl = (const float*)d_in[7];
    // d_in[8] (bl) cancels under softmax shift-invariance; not read.

    float* ws = (float*)d_ws;
    float* Eq = ws + QP_OFF;
    float* Ek = ws + KP_OFF;
    unsigned char* mcan = (unsigned char*)(ws + MASK_OFF);
    unsigned short* Whi  = (unsigned short*)(ws + WH_OFF);
    unsigned short* Wlo  = (unsigned short*)(ws + WL_OFF);
    unsigned short* MThi = (unsigned short*)(ws + MT_H_OFF);
    unsigned short* MTlo = (unsigned short*)(ws + MT_L_OFF);
    unsigned short* Wbhi = (unsigned short*)(ws + WB_H_OFF);
    unsigned short* Wblo = (unsigned short*)(ws + WB_L_OFF);

    float* attns = (float*)d_out;                      // [B][QL][KS]
    float* wout  = (float*)d_out + B_ * QL_ * KS_;     // [B][QL][ML] (also sr scratch)

    prep_kernel<<<dim3(1089), dim3(256), 0, stream>>>(memory, Wq, Wk, Whi, Wlo,
                                                      MThi, MTlo, mask, mcan);
    proj_kernel<<<dim3(576), dim3(256), 0, stream>>>(query, memory, Whi, Wlo,
                                                     bq, bk, Eq, Ek);
    logits_kernel<<<dim3(1024), dim3(256), 0, stream>>>(Eq, Ek, wl, wout);
    softmax_kernel<<<dim3(B_ * QL_), dim3(256), 0, stream>>>(wout, mcan, Wbhi, Wblo);
    attn_out_kernel<<<dim3(512), dim3(256), 0, stream>>>(Wbhi, Wblo, MThi, MTlo, attns);
}

// Round 7
// 156.906 us; speedup vs baseline: 1.4808x; 1.0577x over previous
//
#include <hip/hip_runtime.h>

#define B_  8
#define QL_ 128
#define ML_ 1024
#define KS_ 512
#define H_  256

// ws layout (floats):
//   Eq (h-PERMUTED) [B][QL][H]            @ 0        (262144)
//   Ek (h-PERMUTED) [B][ML][H]            @ 262144   (2097152)
//   mask canonical uint8 [B*ML]           @ 2359296  (2048 float slots)
//   Whi bf16 [512][512]                   @ 2361344  (131072)
//   Wlo bf16 [512][512]                   @ 2492416  (131072)
//   MThi bf16 [8][512][1024] (memory^T)   @ 2623488  (2097152)
//   MTlo bf16 [8][512][1024]              @ 4720640  (2097152)
//   Wbhi bf16 [8][128][1024] (weights)    @ 6817792  (524288)
//   Wblo bf16 [8][128][1024]              @ 7342080  (524288)
//   Xhi bf16 [9216][512] (query|memory)   @ 7866368  (2359296)
//   Xlo bf16 [9216][512]                  @ 10225664 (2359296)
//   wlp (h-PERMUTED wl) [256]             @ 12584960 (256)
// h-permutation (within each 8-group): orig index o -> pos ((o&3)<<1)|(o>>2),
// i.e. (h0,h4,h1,h5,h2,h6,h3,h7) -> consecutive PAIRS are (h_j, h_{j+4}),
// enabling packed-f32 (v_pk_fma_f32) processing of two rcp-quads at once.
#define QP_OFF 0
#define KP_OFF 262144
#define MASK_OFF 2359296
#define WH_OFF 2361344
#define WL_OFF 2492416
#define MT_H_OFF 2623488
#define MT_L_OFF 4720640
#define WB_H_OFF 6817792
#define WB_L_OFF 7342080
#define XH_OFF 7866368
#define XL_OFF 10225664
#define WLP_OFF 12584960

typedef __attribute__((ext_vector_type(8))) short bfrag;   // 8 bf16 (4 VGPR)
typedef __attribute__((ext_vector_type(4))) float f4acc;   // MFMA acc
typedef __attribute__((ext_vector_type(2))) float f2;      // packed f32 pair

// fp32 -> (hi,lo) bf16 split. hi = truncation (residual <= 2^-8|x|, captured
// exactly by fp32 subtract); lo = RNE of residual (final err <= 2^-17|x|).
__device__ __forceinline__ void split1(float v, unsigned& h, unsigned& lo) {
    unsigned u  = __float_as_uint(v);
    unsigned hb = u & 0xFFFF0000u;
    float    lf = v - __uint_as_float(hb);           // exact
    unsigned ul = __float_as_uint(lf);
    unsigned lr = ul + 0x7FFFu + ((ul >> 16) & 1u);  // RNE
    h  = u >> 16;
    lo = lr >> 16;
}

__device__ __forceinline__ void split4(const float4& a, unsigned& h01, unsigned& h23,
                                       unsigned& l01, unsigned& l23) {
    unsigned h[4], l[4];
    split1(a.x, h[0], l[0]); split1(a.y, h[1], l[1]);
    split1(a.z, h[2], l[2]); split1(a.w, h[3], l[3]);
    h01 = h[0] | (h[1] << 16); h23 = h[2] | (h[3] << 16);
    l01 = l[0] | (l[1] << 16); l23 = l[2] | (l[3] << 16);
}

// ---------------------------------------------------------------------------
// Prep kernel, grid 2241 x 256:
//   bid 0..63     : W split (Wq rows 0..255, Wk rows 256..511 of Whi/Wlo)
//   bid 64..191   : query  -> Xhi/Xlo rows 0..1023
//   bid 192..1215 : memory -> Xhi/Xlo rows 1024..9215
//   bid 1216..2239: memory transpose-split -> MThi/MTlo[b][s][m]
//   bid 2240      : mask canonicalizer + permuted-wl copy
// All memory-bound (~60 MB total ≈ 10 us).
// ---------------------------------------------------------------------------
__global__ __launch_bounds__(256) void prep_kernel(
    const float* __restrict__ query, const float* __restrict__ memory,
    const float* __restrict__ Wq, const float* __restrict__ Wk,
    const float* __restrict__ wl,
    unsigned short* __restrict__ Whi, unsigned short* __restrict__ Wlo,
    unsigned short* __restrict__ Xhi, unsigned short* __restrict__ Xlo,
    unsigned short* __restrict__ MThi, unsigned short* __restrict__ MTlo,
    const unsigned char* __restrict__ mraw, unsigned char* __restrict__ mout,
    float* __restrict__ wlp) {
    const int bid = blockIdx.x;
    const int t = threadIdx.x;

    if (bid == 2240) {   // ---- mask canonicalizer + wl permute ----
        // permuted wl: within each 8-group, orig o -> pos ((o&3)<<1)|(o>>2)
        wlp[(t & ~7) | (((t & 3) << 1) | ((t >> 2) & 1))] = wl[t];
        __shared__ int s_not01, s_not0f;
        const unsigned int* w = (const unsigned int*)mraw;
        if (t == 0) { s_not01 = 0; s_not0f = 0; }
        __syncthreads();
        int not01 = 0, not0f = 0;
        for (int i = t; i < 2048; i += 256) {
            unsigned int v = w[i];
            if (v != 0u && v != 1u) not01 = 1;
            if (v != 0u && v != 0x3F800000u) not0f = 1;
        }
        if (not01) atomicOr(&s_not01, 1);
        if (not0f) atomicOr(&s_not0f, 1);
        __syncthreads();
        int wordTyped = (!s_not01) || (!s_not0f);
        for (int i = t; i < B_ * ML_; i += 256) {
            unsigned char mv;
            if (wordTyped) mv = (w[i] != 0u) ? 1 : 0;
            else           mv = mraw[i] ? 1 : 0;
            mout[i] = mv;
        }
        return;
    }

    if (bid >= 1216) {   // ---- memory transpose-split (64x64 tile via LDS) ----
        const int idx = bid - 1216;     // 0..1023
        const int b  = idx >> 7;
        const int r  = idx & 127;
        const int mt = r >> 3;          // m tile (16 of 64 rows)
        const int st = r & 7;           // s tile (8 of 64 cols)
        __shared__ float T[64][68];

        const int i  = t >> 2, jb = (t & 3) << 4;
        const float* mp = memory + ((size_t)(b * ML_ + mt * 64 + i)) * KS_ + st * 64 + jb;
#pragma unroll
        for (int q = 0; q < 4; ++q)
            *(float4*)(&T[i][jb + q * 4]) = *(const float4*)(mp + q * 4);
        __syncthreads();

        const int s = t >> 2, mb = (t & 3) << 4;
        unsigned hh[16], ll[16];
#pragma unroll
        for (int e = 0; e < 16; ++e) split1(T[mb + e][s], hh[e], ll[e]);
        unsigned hp[8], lp[8];
#pragma unroll
        for (int e = 0; e < 8; ++e) {
            hp[e] = hh[2 * e] | (hh[2 * e + 1] << 16);
            lp[e] = ll[2 * e] | (ll[2 * e + 1] << 16);
        }
        const size_t doff = ((size_t)(b * KS_ + st * 64 + s)) * ML_ + mt * 64 + mb;
        *(uint4*)(MThi + doff)     = make_uint4(hp[0], hp[1], hp[2], hp[3]);
        *(uint4*)(MThi + doff + 8) = make_uint4(hp[4], hp[5], hp[6], hp[7]);
        *(uint4*)(MTlo + doff)     = make_uint4(lp[0], lp[1], lp[2], lp[3]);
        *(uint4*)(MTlo + doff + 8) = make_uint4(lp[4], lp[5], lp[6], lp[7]);
        return;
    }

    // ---- linear hi/lo splits: W planes and X planes ----
    const float* src; unsigned short *dh, *dl; size_t soff, doff;
    if (bid < 64) {
        src = (bid < 32) ? Wq : Wk;
        soff = (size_t)(bid & 31) * 4096;
        doff = ((bid < 32) ? 0 : 131072) + soff;
        dh = Whi; dl = Wlo;
    } else if (bid < 192) {
        src = query;  soff = (size_t)(bid - 64) * 4096;  doff = soff;
        dh = Xhi; dl = Xlo;
    } else {
        src = memory; soff = (size_t)(bid - 192) * 4096; doff = 524288 + soff;
        dh = Xhi; dl = Xlo;
    }
    soff += (size_t)t * 16; doff += (size_t)t * 16;

    unsigned hw[8], lw[8];
#pragma unroll
    for (int i = 0; i < 4; ++i) {
        float4 v = *(const float4*)(src + soff + i * 4);
        split4(v, hw[i * 2], hw[i * 2 + 1], lw[i * 2], lw[i * 2 + 1]);
    }
    *(uint4*)(dh + doff)     = make_uint4(hw[0], hw[1], hw[2], hw[3]);
    *(uint4*)(dh + doff + 8) = make_uint4(hw[4], hw[5], hw[6], hw[7]);
    *(uint4*)(dl + doff)     = make_uint4(lw[0], lw[1], lw[2], lw[3]);
    *(uint4*)(dl + doff + 8) = make_uint4(lw[4], lw[5], lw[6], lw[7]);
}

// ---------------------------------------------------------------------------
// Projection via bf16x3-split MFMA — attn_out-style schedule (the session's
// only directly-validated fast GEMM pattern). R6-proj's MFMA pipe time was
// ~0.9us of a 42us kernel (2% util, ~97% stall: in-loop split VALU +
// 2 barriers/chunk + 1-chunk prefetch < L2 latency). Now: both operands
// pre-split in global (prep) -> staging is pure copy; BK=64, 1 barrier/chunk,
// reg-prefetch 2 chunks ahead; grid 1152 (4.5 blocks/CU, LDS-capped 3
// resident). Full-permutation XOR swizzle (oct ^= row&7) -> conflict-free.
// Accumulation order identical to R2..R6 (K=32 slices ascending, hi*hi,
// hi*lo, lo*hi) -> Eq/Ek values bit-identical; stores are h-PERMUTED
// (column remap within 8-groups) for logits' packed-f32 consumption.
// ---------------------------------------------------------------------------
__global__ __launch_bounds__(256) void proj_kernel(
    const unsigned short* __restrict__ Xhi, const unsigned short* __restrict__ Xlo,
    const unsigned short* __restrict__ Whi, const unsigned short* __restrict__ Wlo,
    const float* __restrict__ bq, const float* __restrict__ bk,
    float* __restrict__ Eq, float* __restrict__ Ek) {
    const int bid = blockIdx.x;
    const int t = threadIdx.x;
    // XCD-chunked bijective swizzle (1152 = 8*144)
    const int wk = (bid & 7) * 144 + (bid >> 3);
    const int nt = wk & 3;           // n tile of 64
    const int mt = wk >> 2;          // m tile of 32 (0..287)

    const bool isQ = (mt < 32);
    const int arow0 = mt * 32;                        // row in X planes
    const int orow0 = isQ ? arow0 : arow0 - 1024;     // row in output
    const float* bias = isQ ? bq : bk;
    float* out = isQ ? Eq : Ek;
    const int wrb = (isQ ? 0 : 256) + nt * 64;        // W-plane row base

    const int w  = t >> 6;
    const int wm = w >> 1, wn = w & 1;   // wave = 16m x 32n
    const int l  = t & 63;
    const int lr = l & 15, lk = l >> 4;

    __shared__ unsigned short As[2][2][32][64];   // [buf][plane][row][k]
    __shared__ unsigned short Bs[2][2][64][64];

    // staging maps: plane p = t>>7; slot = t&127
    const int pa   = t >> 7;
    const int slot = t & 127;
    const int arow = slot >> 2, ao = slot & 3;         // A octs ao, ao+4
    const int brow = slot >> 1, bo0 = (slot & 1) * 4;  // B octs bo0..bo0+3
    const unsigned short* asrc = (pa ? Xlo : Xhi) + (size_t)(arow0 + arow) * 512 + ao * 8;
    const unsigned short* bsrc = (pa ? Wlo : Whi) + (size_t)(wrb + brow) * 512 + bo0 * 8;
    const int awd0 = (ao ^ (arow & 7)) * 8;
    const int awd1 = ((ao + 4) ^ (arow & 7)) * 8;
    int bwd[4];
#pragma unroll
    for (int i = 0; i < 4; ++i) bwd[i] = ((bo0 + i) ^ (brow & 7)) * 8;

    f4acc acc[2];
    acc[0] = (f4acc){0.f, 0.f, 0.f, 0.f};
    acc[1] = (f4acc){0.f, 0.f, 0.f, 0.f};

    uint4 g0a0, g0a1, g0b0, g0b1, g0b2, g0b3;
    uint4 g1a0, g1a1, g1b0, g1b1, g1b2, g1b3;

#define LOADG(G, c) do {                                                  \
    G##a0 = *(const uint4*)(asrc + (size_t)(c) * 64);                     \
    G##a1 = *(const uint4*)(asrc + (size_t)(c) * 64 + 32);                \
    G##b0 = *(const uint4*)(bsrc + (size_t)(c) * 64);                     \
    G##b1 = *(const uint4*)(bsrc + (size_t)(c) * 64 + 8);                 \
    G##b2 = *(const uint4*)(bsrc + (size_t)(c) * 64 + 16);                \
    G##b3 = *(const uint4*)(bsrc + (size_t)(c) * 64 + 24); } while (0)

#define WRITEB(P, G) do {                                                 \
    *(uint4*)(&As[P][pa][arow][awd0])  = G##a0;                           \
    *(uint4*)(&As[P][pa][arow][awd1])  = G##a1;                           \
    *(uint4*)(&Bs[P][pa][brow][bwd[0]]) = G##b0;                          \
    *(uint4*)(&Bs[P][pa][brow][bwd[1]]) = G##b1;                          \
    *(uint4*)(&Bs[P][pa][brow][bwd[2]]) = G##b2;                          \
    *(uint4*)(&Bs[P][pa][brow][bwd[3]]) = G##b3; } while (0)

#define COMPUTE(P) do {                                                   \
    _Pragma("unroll")                                                     \
    for (int ks = 0; ks < 2; ++ks) {                                      \
        const int ra = wm * 16 + lr;                                      \
        const int koA = ((ks * 4 + lk) ^ (ra & 7)) * 8;                   \
        bfrag ah = *(const bfrag*)&As[P][0][ra][koA];                     \
        bfrag al = *(const bfrag*)&As[P][1][ra][koA];                     \
        _Pragma("unroll")                                                 \
        for (int ni = 0; ni < 2; ++ni) {                                  \
            const int rb = wn * 32 + ni * 16 + lr;                        \
            const int koB = ((ks * 4 + lk) ^ (rb & 7)) * 8;               \
            bfrag bh = *(const bfrag*)&Bs[P][0][rb][koB];                 \
            bfrag bl = *(const bfrag*)&Bs[P][1][rb][koB];                 \
            acc[ni] = __builtin_amdgcn_mfma_f32_16x16x32_bf16(            \
                ah, bh, acc[ni], 0, 0, 0);                                \
            acc[ni] = __builtin_amdgcn_mfma_f32_16x16x32_bf16(            \
                ah, bl, acc[ni], 0, 0, 0);                                \
            acc[ni] = __builtin_amdgcn_mfma_f32_16x16x32_bf16(            \
                al, bh, acc[ni], 0, 0, 0);                                \
        }                                                                 \
    } } while (0)

    LOADG(g0, 0);
    WRITEB(0, g0);
    LOADG(g1, 1);
    __syncthreads();

#pragma unroll
    for (int c = 0; c < 8; ++c) {
        if (c + 1 < 8) {
            if ((c + 1) & 1) WRITEB(1, g1); else WRITEB(0, g0);
        }
        if (c + 2 < 8) {
            if (c & 1) LOADG(g1, c + 2); else LOADG(g0, c + 2);
        }
        COMPUTE(c & 1);
        __syncthreads();
    }
#undef LOADG
#undef WRITEB
#undef COMPUTE

    // epilogue: bias + exp2; store at h-PERMUTED column
    const float SC = 2.885390081777926815f;   // 2*log2(e)
#pragma unroll
    for (int ni = 0; ni < 2; ++ni) {
        const int col = nt * 64 + wn * 32 + ni * 16 + lr;   // original h
        const int colp = (col & ~7) | (((col & 3) << 1) | ((col >> 2) & 1));
        const float bc = bias[col];
#pragma unroll
        for (int rr = 0; rr < 4; ++rr) {
            const int row = orow0 + wm * 16 + lk * 4 + rr;
            out[(size_t)row * 256 + colp] =
                __builtin_amdgcn_exp2f(SC * (acc[ni][rr] + bc));
        }
    }
}

// ---------------------------------------------------------------------------
// logits: sr[b][q][m] = sum_h wl[h]/(Eq*Ek+1), packed-f32 rewrite.
// R6: 43us at VALUBusy 56% -> instruction-count-bound (~24us VALU). CDNA4
// dual-pumped v_pk_fma_f32: process the two rcp-quads of each orig 8-h group
// element-wise as float2 (h-permuted layout makes (h_j,h_{j+4}) adjacent).
// Quad term VALUES bit-identical to R6 (quadA = orig h0-3, quadB = h4-7);
// only cross-quad sum order interleaves (~1e-7). 14 pk + 2 rcp per 8h vs
// 30 scalar = 1.9x fewer VALU instr. Staging/geometry unchanged from R6.
// ---------------------------------------------------------------------------
__device__ __forceinline__ f2 qterm8(const float4 k4a, const float4 k4b,
                                     const float4 q4a, const float4 q4b,
                                     const float4 w4a, const float4 w4b,
                                     f2 acc) {
    f2 kp0 = {k4a.x, k4a.y}, kp1 = {k4a.z, k4a.w};
    f2 kp2 = {k4b.x, k4b.y}, kp3 = {k4b.z, k4b.w};
    f2 qp0 = {q4a.x, q4a.y}, qp1 = {q4a.z, q4a.w};
    f2 qp2 = {q4b.x, q4b.y}, qp3 = {q4b.z, q4b.w};
    f2 wp0 = {w4a.x, w4a.y}, wp1 = {w4a.z, w4a.w};
    f2 wp2 = {w4b.x, w4b.y}, wp3 = {w4b.z, w4b.w};
    const f2 one2 = {1.0f, 1.0f};
    f2 pp0 = __builtin_elementwise_fma(kp0, qp0, one2);
    f2 pp1 = __builtin_elementwise_fma(kp1, qp1, one2);
    f2 pp2 = __builtin_elementwise_fma(kp2, qp2, one2);
    f2 pp3 = __builtin_elementwise_fma(kp3, qp3, one2);
    f2 p01 = pp0 * pp1, p23 = pp2 * pp3;
    f2 n01 = __builtin_elementwise_fma(wp1, pp0, wp0 * pp1);
    f2 n23 = __builtin_elementwise_fma(wp3, pp2, wp2 * pp3);
    f2 Nm  = __builtin_elementwise_fma(n23, p01, n01 * p23);
    f2 P   = p01 * p23;
    f2 r   = {__builtin_amdgcn_rcpf(P.x), __builtin_amdgcn_rcpf(P.y)};
    return __builtin_elementwise_fma(Nm, r, acc);
}

__global__ __launch_bounds__(256) void logits_kernel(
    const float* __restrict__ Eq, const float* __restrict__ Ek,
    const float* __restrict__ wlp, float* __restrict__ sr) {
    const int bid = blockIdx.x;
    const int b  = bid & 7;
    const int r2 = bid >> 3;
    const int mt = r2 & 7;      // m tile of 128
    const int qt = r2 >> 3;     // q octet
    const int tid = threadIdx.x;
    const int m  = tid & 127;
    const int qh = __builtin_amdgcn_readfirstlane(tid >> 7);  // wave-uniform

    __shared__ float kq[2][4][128][4];   // [buf][h'-quad][m][4]

    const float* qpb = Eq + ((size_t)(b * QL_ + qt * 8 + qh * 4)) * H_;
    const float* kpb = Ek + ((size_t)(b * ML_ + mt * 128)) * H_;

    const int srow = tid & 127;
    const int sq2  = tid >> 7;
    const float* kst = kpb + (size_t)srow * H_ + 8 * sq2;

    float4 a0 = *(const float4*)(kst);
    float4 a1 = *(const float4*)(kst + 4);
    *(float4*)(&kq[0][2 * sq2 + 0][srow][0]) = a0;
    *(float4*)(&kq[0][2 * sq2 + 1][srow][0]) = a1;
    a0 = *(const float4*)(kst + 16);
    a1 = *(const float4*)(kst + 20);
    __syncthreads();

    f2 accp[4];
#pragma unroll
    for (int j2 = 0; j2 < 4; ++j2) accp[j2] = (f2){0.f, 0.f};

    for (int c = 0; c < 16; ++c) {
        const int cb = c & 1;
        if (c < 15) {
            *(float4*)(&kq[cb ^ 1][2 * sq2 + 0][srow][0]) = a0;
            *(float4*)(&kq[cb ^ 1][2 * sq2 + 1][srow][0]) = a1;
            if (c < 14) {
                a0 = *(const float4*)(kst + (c + 2) * 16);
                a1 = *(const float4*)(kst + (c + 2) * 16 + 4);
            }
        }
        const int h0 = c * 16;
#pragma unroll
        for (int pg = 0; pg < 2; ++pg) {
            float4 k4a = *(const float4*)(&kq[cb][2 * pg + 0][m][0]);
            float4 k4b = *(const float4*)(&kq[cb][2 * pg + 1][m][0]);
            float4 w4a = *(const float4*)(wlp + h0 + pg * 8);
            float4 w4b = *(const float4*)(wlp + h0 + pg * 8 + 4);
#pragma unroll
            for (int j2 = 0; j2 < 4; ++j2) {
                float4 q4a = *(const float4*)(qpb + (size_t)j2 * H_ + h0 + pg * 8);
                float4 q4b = *(const float4*)(qpb + (size_t)j2 * H_ + h0 + pg * 8 + 4);
                accp[j2] = qterm8(k4a, k4b, q4a, q4b, w4a, w4b, accp[j2]);
            }
        }
        __syncthreads();
    }
#pragma unroll
    for (int j2 = 0; j2 < 4; ++j2)
        sr[((size_t)(b * QL_ + qt * 8 + qh * 4 + j2)) * ML_ + mt * 128 + m] =
            accp[j2].x + accp[j2].y;
}

// ---------------------------------------------------------------------------
// In-place masked softmax + bf16 hi/lo split of weights for the MFMA
// attn_out (A-operand). logits_eff = -2*sr (shift-invariant). (unchanged)
// ---------------------------------------------------------------------------
__global__ __launch_bounds__(256) void softmax_kernel(
    float* __restrict__ wrow_io, const unsigned char* __restrict__ mv,
    unsigned short* __restrict__ Wbhi, unsigned short* __restrict__ Wblo) {
    const int row = blockIdx.x;
    const int b = row >> 7;
    const int tid = threadIdx.x;
    float* srow = wrow_io + (size_t)row * ML_;
    const unsigned char* mrow = mv + b * ML_;
    __shared__ float red[4];

    float4 s4 = *(const float4*)(srow + tid * 4);
    uchar4 m4 = *(const uchar4*)(mrow + tid * 4);
    float l[4];
    l[0] = m4.x ? -1e18f : -2.0f * s4.x;
    l[1] = m4.y ? -1e18f : -2.0f * s4.y;
    l[2] = m4.z ? -1e18f : -2.0f * s4.z;
    l[3] = m4.w ? -1e18f : -2.0f * s4.w;

    float mx = fmaxf(fmaxf(l[0], l[1]), fmaxf(l[2], l[3]));
#pragma unroll
    for (int off = 32; off >= 1; off >>= 1)
        mx = fmaxf(mx, __shfl_xor(mx, off));
    if ((tid & 63) == 0) red[tid >> 6] = mx;
    __syncthreads();
    mx = fmaxf(fmaxf(red[0], red[1]), fmaxf(red[2], red[3]));
    __syncthreads();

    const float L2E = 1.44269504088896340736f;
    float e[4], s = 0.f;
#pragma unroll
    for (int i = 0; i < 4; ++i) {
        e[i] = __builtin_amdgcn_exp2f((l[i] - mx) * L2E);
        s += e[i];
    }
#pragma unroll
    for (int off = 32; off >= 1; off >>= 1)
        s += __shfl_xor(s, off);
    if ((tid & 63) == 0) red[tid >> 6] = s;
    __syncthreads();
    s = (red[0] + red[1]) + (red[2] + red[3]);
    float inv = __builtin_amdgcn_rcpf(s);
    float4 o = make_float4(e[0] * inv, e[1] * inv, e[2] * inv, e[3] * inv);
    *(float4*)(srow + tid * 4) = o;

    unsigned h01, h23, l01, l23;
    split4(o, h01, h23, l01, l23);
    *(uint2*)(Wbhi + (size_t)row * ML_ + tid * 4) = make_uint2(h01, h23);
    *(uint2*)(Wblo + (size_t)row * ML_ + tid * 4) = make_uint2(l01, l23);
}

// ---------------------------------------------------------------------------
// attns[b] = weights[b] (128x1024) @ memory[b] (1024x512), bf16x3 MFMA.
// (unchanged from R6 — this schedule is the validated-fast pattern)
// ---------------------------------------------------------------------------
__global__ __launch_bounds__(256) void attn_out_kernel(
    const unsigned short* __restrict__ Wbhi, const unsigned short* __restrict__ Wblo,
    const unsigned short* __restrict__ MThi, const unsigned short* __restrict__ MTlo,
    float* __restrict__ out) {
    const int bid = blockIdx.x;
    const int b  = bid & 7;
    const int r  = bid >> 3;          // 0..63
    const int mt = r & 7;             // m tile of 16
    const int nt = r >> 3;            // n tile of 64
    const int t = threadIdx.x;
    const int w  = t >> 6;
    const int l  = t & 63;
    const int lr = l & 15, lk = l >> 4;

    __shared__ unsigned short As[2][16][2][64];   // [buf][row][plane][k]
    __shared__ unsigned short Bs[2][64][2][64];

    const int pa  = t >> 7;
    const int ar  = (t >> 3) & 15;
    const int acq = t & 7;
    const unsigned short* asrc = (pa ? Wblo : Wbhi)
        + ((size_t)(b * QL_ + mt * 16 + ar)) * ML_ + acq * 8;
    const int aws = (acq ^ (ar & 7)) * 8;

    const int pb  = t >> 7;
    const int br  = (t & 127) >> 1;
    const int bq0 = (t & 1) * 4;
    const unsigned short* bsrc = (pb ? MTlo : MThi)
        + ((size_t)(b * KS_ + nt * 64 + br)) * ML_ + bq0 * 8;
    int bws[4];
#pragma unroll
    for (int i2 = 0; i2 < 4; ++i2) bws[i2] = ((bq0 + i2) ^ (br & 7)) * 8;

    f4acc acc = (f4acc){0.f, 0.f, 0.f, 0.f};

    uint4 g0a, g0b0, g0b1, g0b2, g0b3;
    uint4 g1a, g1b0, g1b1, g1b2, g1b3;

#define LOADG(G, c) do {                                                  \
    G##a  = *(const uint4*)(asrc + (size_t)(c) * 64);                     \
    G##b0 = *(const uint4*)(bsrc + (size_t)(c) * 64);                     \
    G##b1 = *(const uint4*)(bsrc + (size_t)(c) * 64 + 8);                 \
    G##b2 = *(const uint4*)(bsrc + (size_t)(c) * 64 + 16);                \
    G##b3 = *(const uint4*)(bsrc + (size_t)(c) * 64 + 24); } while (0)

#define WRITEB(P, G) do {                                                 \
    *(uint4*)(&As[P][ar][pa][aws])    = G##a;                             \
    *(uint4*)(&Bs[P][br][pb][bws[0]]) = G##b0;                            \
    *(uint4*)(&Bs[P][br][pb][bws[1]]) = G##b1;                            \
    *(uint4*)(&Bs[P][br][pb][bws[2]]) = G##b2;                            \
    *(uint4*)(&Bs[P][br][pb][bws[3]]) = G##b3; } while (0)

#define COMPUTE(P) do {                                                   \
    _Pragma("unroll")                                                     \
    for (int ks = 0; ks < 2; ++ks) {                                      \
        const int k8 = (ks * 4 + lk) ^ (lr & 7);                          \
        bfrag ah = *(const bfrag*)&As[P][lr][0][k8 * 8];                  \
        bfrag al = *(const bfrag*)&As[P][lr][1][k8 * 8];                  \
        bfrag bh = *(const bfrag*)&Bs[P][w * 16 + lr][0][k8 * 8];         \
        bfrag bl = *(const bfrag*)&Bs[P][w * 16 + lr][1][k8 * 8];         \
        acc = __builtin_amdgcn_mfma_f32_16x16x32_bf16(ah, bh, acc, 0,0,0);\
        acc = __builtin_amdgcn_mfma_f32_16x16x32_bf16(ah, bl, acc, 0,0,0);\
        acc = __builtin_amdgcn_mfma_f32_16x16x32_bf16(al, bh, acc, 0,0,0);\
    } } while (0)

    LOADG(g0, 0);
    WRITEB(0, g0);
    LOADG(g1, 1);
    __syncthreads();

#pragma unroll
    for (int c = 0; c < 16; ++c) {
        if (c + 1 < 16) {
            if ((c + 1) & 1) WRITEB(1, g1); else WRITEB(0, g0);
        }
        if (c + 2 < 16) {
            if (c & 1) LOADG(g1, c + 2); else LOADG(g0, c + 2);
        }
        COMPUTE(c & 1);
        __syncthreads();
    }
#undef LOADG
#undef WRITEB
#undef COMPUTE

    const int col = nt * 64 + w * 16 + lr;
#pragma unroll
    for (int rr = 0; rr < 4; ++rr) {
        const int row = mt * 16 + lk * 4 + rr;
        out[((size_t)(b * QL_ + row)) * KS_ + col] = acc[rr];
    }
}

extern "C" void kernel_launch(void* const* d_in, const int* in_sizes, int n_in,
                              void* d_out, int out_size, void* d_ws, size_t ws_size,
                              hipStream_t stream) {
    const float* query  = (const float*)d_in[0];
    const float* memory = (const float*)d_in[1];
    const unsigned char* mask = (const unsigned char*)d_in[2];
    const float* Wq = (const float*)d_in[3];
    const float* bq = (const float*)d_in[4];
    const float* Wk = (const float*)d_in[5];
    const float* bk = (const float*)d_in[6];
    const float* wl = (const float*)d_in[7];
    // d_in[8] (bl) cancels under softmax shift-invariance; not read.

    float* ws = (float*)d_ws;
    float* Eq = ws + QP_OFF;
    float* Ek = ws + KP_OFF;
    unsigned char* mcan = (unsigned char*)(ws + MASK_OFF);
    unsigned short* Whi  = (unsigned short*)(ws + WH_OFF);
    unsigned short* Wlo  = (unsigned short*)(ws + WL_OFF);
    unsigned short* MThi = (unsigned short*)(ws + MT_H_OFF);
    unsigned short* MTlo = (unsigned short*)(ws + MT_L_OFF);
    unsigned short* Wbhi = (unsigned short*)(ws + WB_H_OFF);
    unsigned short* Wblo = (unsigned short*)(ws + WB_L_OFF);
    unsigned short* Xhi  = (unsigned short*)(ws + XH_OFF);
    unsigned short* Xlo  = (unsigned short*)(ws + XL_OFF);
    float* wlp = ws + WLP_OFF;

    float* attns = (float*)d_out;                      // [B][QL][KS]
    float* wout  = (float*)d_out + B_ * QL_ * KS_;     // [B][QL][ML] (also sr scratch)

    prep_kernel<<<dim3(2241), dim3(256), 0, stream>>>(query, memory, Wq, Wk, wl,
                                                      Whi, Wlo, Xhi, Xlo,
                                                      MThi, MTlo, mask, mcan, wlp);
    proj_kernel<<<dim3(1152), dim3(256), 0, stream>>>(Xhi, Xlo, Whi, Wlo,
                                                      bq, bk, Eq, Ek);
    logits_kernel<<<dim3(1024), dim3(256), 0, stream>>>(Eq, Ek, wlp, wout);
    softmax_kernel<<<dim3(B_ * QL_), dim3(256), 0, stream>>>(wout, mcan, Wbhi, Wblo);
    attn_out_kernel<<<dim3(512), dim3(256), 0, stream>>>(Wbhi, Wblo, MThi, MTlo, attns);
}